// Round 22
// baseline (51.510 us; speedup 1.0000x reference)
//
#include <hip/hip_runtime.h>
#include <hip/hip_fp16.h>
#include <cstddef>

#define DIM 2048
#define NTOK 8192
#define NEUMANN_ITERS 6
#define PLANE (DIM / 2 + 1)   // +1 uint4 pad: plane stride 4100 words = 4 banks

// Math (validated rounds 1-21):
//   omega = P Q^T, P=[U|V], Q=[sV|-sU], G = Q^T P  (16x16)
//   Y = (I - G/2)^{-1}(I + G/2)  via Neumann-Horner: Y <- B + 0.5*G*Y, B=I+G/2
//   out = x + c . W^T,  c[r][k] = 0.5*s * sum_j Z[k][j] b[r][j],  Z = I + Y,
//     b[j<8] = av[j], b[j>=8] = -au[j-8];  a = [x.U | x.V] = x.W
//
// r21 (MFMA, 256thr): 40.5us steady, MfmaUtil 1.8 / VALU 12 / hbm 41 /
// occ 16% (8 waves/CU) + 905K bank conflicts (uvQ planes 16KB apart =
// 0 mod 32 banks). THIS round:
//   - 512 thr = 2 independent 4-wave teams sharing staging+preamble;
//     16 rows/team, 32/block, grid 256 -> 16 waves/CU (2x TLP).
//   - uvQ plane padded +1 uint4 -> planes 4 banks apart; phase-1 group
//     gather hits 16 distinct banks, phase-2 planes de-conflict.
//   - MFMA 16x16x16f16 layout per m89 (A row=l&15, k=(l>>4)*4+j; B
//     col=l&15; D col=l&15, row=(l>>4)*4+reg); f32 accumulation.
//   - 512-thr caps VGPR at 128 (r21 used 88 -> fits; r19's 1024-thr/64
//     trap avoided). No min-waves clause (r6).

typedef _Float16 h4 __attribute__((ext_vector_type(4)));
typedef float f32x4 __attribute__((ext_vector_type(4)));

__device__ __forceinline__ unsigned pkh(float lo, float hi) {
  auto p = __builtin_amdgcn_cvt_pkrtz(lo, hi);   // v_cvt_pkrtz_f16_f32
  return __builtin_bit_cast(unsigned, p);
}

// ---------------------------------------------------------------------------
// 1) Gram: one block per entry e=(q,i,j); 256 threads reduce over d=2048.
// ---------------------------------------------------------------------------
__global__ __launch_bounds__(256) void rora_gram(
    const float* __restrict__ U, const float* __restrict__ V,
    float* __restrict__ prod) {
  const int e = blockIdx.x;            // 0..191
  const int q = e >> 6;                // 0: U^T U, 1: U^T V, 2: V^T V
  const int i = (e >> 3) & 7, j = e & 7;
  const float* A = (q == 2) ? V : U;
  const float* B = (q == 0) ? U : V;
  const int t = threadIdx.x;
  float acc = 0.f;
#pragma unroll
  for (int s = 0; s < 8; ++s) {
    const int d = s * 256 + t;
    acc = fmaf(A[d * 8 + i], B[d * 8 + j], acc);
  }
#pragma unroll
  for (int m = 1; m < 64; m <<= 1) acc += __shfl_xor(acc, m, 64);
  __shared__ float wsum[4];
  if ((t & 63) == 0) wsum[t >> 6] = acc;
  __syncthreads();
  if (t == 0) prod[e] = (wsum[0] + wsum[1]) + (wsum[2] + wsum[3]);
}

// ---------------------------------------------------------------------------
// 2) Fused MFMA kernel. uvQ[q][P].comp(m) = half2(W[2P][4q+m], W[2P+1][4q+m]).
//    512 thr = 2 teams x 4 waves; 16 rows/team; grid 256.
// ---------------------------------------------------------------------------
__global__ __launch_bounds__(512) void rora_fused(
    const float* __restrict__ x, const float* __restrict__ U,
    const float* __restrict__ V, const float* __restrict__ gate,
    const float* __restrict__ prod, float* __restrict__ out) {
  __shared__ uint4 uvQ[4][PLANE];     // ~64.1 KB (padded planes)
  __shared__ float prodS[192];
  __shared__ float Gs[16][17];
  __shared__ float Bm[16][17];
  __shared__ float Ya[16][17];
  __shared__ float Yb[16][17];
  __shared__ float Ared[2][4][64][4]; // per-team, per-wave phase-1 partials
  __shared__ float As[2][16][17];     // reduced a[row][k] per team
  const int t = threadIdx.x;          // 0..511
  const int lane = t & 63;
  const int wv8 = t >> 6;             // 0..7
  const int team = wv8 >> 2, wv = wv8 & 3;

  // ---- stage U,V -> LDS as f16 d-pairs (4 pairs per thread) ----
  {
    const float4* U4 = (const float4*)U;
    const float4* V4 = (const float4*)V;
#pragma unroll
    for (int rep = 0; rep < 4; ++rep) {
      const int P = rep * 512 + t;    // d-pair (2P, 2P+1); 0..2047
      const float4 a0 = U4[4 * P + 0], a1 = U4[4 * P + 1];
      const float4 a2 = U4[4 * P + 2], a3 = U4[4 * P + 3];
      const float4 b0 = V4[4 * P + 0], b1 = V4[4 * P + 1];
      const float4 b2 = V4[4 * P + 2], b3 = V4[4 * P + 3];
      uvQ[0][P] = make_uint4(pkh(a0.x, a2.x), pkh(a0.y, a2.y),
                             pkh(a0.z, a2.z), pkh(a0.w, a2.w));
      uvQ[1][P] = make_uint4(pkh(a1.x, a3.x), pkh(a1.y, a3.y),
                             pkh(a1.z, a3.z), pkh(a1.w, a3.w));
      uvQ[2][P] = make_uint4(pkh(b0.x, b2.x), pkh(b0.y, b2.y),
                             pkh(b0.z, b2.z), pkh(b0.w, b2.w));
      uvQ[3][P] = make_uint4(pkh(b1.x, b3.x), pkh(b1.y, b3.y),
                             pkh(b1.z, b3.z), pkh(b1.w, b3.w));
    }
  }

  // ---- 16x16 setup (threads 0..255; barriers block-wide) ----
  if (t < 192) prodS[t] = prod[t];
  __syncthreads();
  const float sg = 1.f / (1.f + expf(-gate[0]));
  if (t < 256) {
    const int r = t >> 4, c = t & 15;
    float g;
    if (r < 8) g = (c < 8) ? sg * prodS[64 + c * 8 + r]              // (V^T U)
                           : sg * prodS[128 + r * 8 + (c - 8)];      // (V^T V)
    else       g = (c < 8) ? -sg * prodS[(r - 8) * 8 + c]            // -(U^T U)
                           : -sg * prodS[64 + (r - 8) * 8 + (c - 8)];
    const float b = ((r == c) ? 1.f : 0.f) + 0.5f * g;
    Gs[r][c] = g;
    Bm[r][c] = b;
    Ya[r][c] = b;
  }
  __syncthreads();
#pragma unroll
  for (int m = 0; m < NEUMANN_ITERS; ++m) {   // ends in Ya (last m odd)
    if (t < 256) {
      const int r = t >> 4, c = t & 15;
      const float (*Yp)[17] = (m & 1) ? Yb : Ya;
      float (*Yn)[17] = (m & 1) ? Ya : Yb;
      float acc = Bm[r][c];
#pragma unroll
      for (int j = 0; j < 16; ++j)
        acc = fmaf(0.5f * Gs[r][j], Yp[j][c], acc);
      Yn[r][c] = acc;
    }
    __syncthreads();   // final barrier also orders uvQ staging
  }

  // ---- phase 1: a = x.W via MFMA; team's wave wv covers K [wv*512,+512) ----
  const int row0 = blockIdx.x * 32 + team * 16;
  const int rA = lane & 15, g = lane >> 4;
  f32x4 acc = {0.f, 0.f, 0.f, 0.f};
  {
    const float* xrow = x + (size_t)(row0 + rA) * DIM;
    const int q1 = rA >> 2, c1 = rA & 3;   // B column k = rA
    const unsigned* uvW = (const unsigned*)&uvQ[q1][0];
#pragma unroll 4
    for (int step = 0; step < 32; ++step) {
      const int d0 = wv * 512 + step * 16 + g * 4;
      const float4 xv = *(const float4*)(xrow + d0);
      uint2 au = {pkh(xv.x, xv.y), pkh(xv.z, xv.w)};
      const h4 af = __builtin_bit_cast(h4, au);
      const int P0 = d0 >> 1;
      uint2 bu = {uvW[P0 * 4 + c1], uvW[(P0 + 1) * 4 + c1]};
      const h4 bf = __builtin_bit_cast(h4, bu);
      acc = __builtin_amdgcn_mfma_f32_16x16x16f16(af, bf, acc, 0, 0, 0);
    }
  }
  Ared[team][wv][lane][0] = acc[0];
  Ared[team][wv][lane][1] = acc[1];
  Ared[team][wv][lane][2] = acc[2];
  Ared[team][wv][lane][3] = acc[3];
  __syncthreads();
  {
    const int l = t & 63, j = (t >> 6) & 3, tm = t >> 8;
    const float s = (Ared[tm][0][l][j] + Ared[tm][1][l][j]) +
                    (Ared[tm][2][l][j] + Ared[tm][3][l][j]);
    As[tm][(l >> 4) * 4 + j][l & 15] = s;   // a[row][k], D layout per m89
  }
  __syncthreads();

  // ---- c fragment (phase-2 A layout: lane holds c[r=rA][g*4+j]) ----
  h4 cf;
  {
    const float hs = 0.5f * sg;
    const int r = rA;
    float cj[4];
#pragma unroll
    for (int j = 0; j < 4; ++j) {
      const int k = g * 4 + j;
      float s = 0.f;
#pragma unroll
      for (int jj = 0; jj < 8; ++jj) {
        const float zA = Ya[k][jj] + ((k == jj) ? 1.f : 0.f);
        const float zB = Ya[k][8 + jj] + ((k == 8 + jj) ? 1.f : 0.f);
        s = fmaf(zA, As[team][r][8 + jj], s);    //  Z[k][j']   * av[j']
        s = fmaf(-zB, As[team][r][jj], s);       // -Z[k][8+j'] * au[j']
      }
      cj[j] = hs * s;
    }
    uint2 cu = {pkh(cj[0], cj[1]), pkh(cj[2], cj[3])};
    cf = __builtin_bit_cast(h4, cu);
  }

  // ---- phase 2: out = x + c.W^T via MFMA; team's wave wv: 32 n-tiles ----
  {
    const int par = rA & 1;
    for (int nt = wv * 32; nt < wv * 32 + 32; ++nt) {
      const int dcol0 = nt * 16;
      const uint4 wq = uvQ[g][(dcol0 + rA) >> 1];  // q = k>>2 = g
      const unsigned w01 = par ? ((wq.x >> 16) | (wq.y & 0xffff0000u))
                               : ((wq.x & 0xffffu) | (wq.y << 16));
      const unsigned w23 = par ? ((wq.z >> 16) | (wq.w & 0xffff0000u))
                               : ((wq.z & 0xffffu) | (wq.w << 16));
      uint2 bu = {w01, w23};
      const h4 bf = __builtin_bit_cast(h4, bu);
      f32x4 z4 = {0.f, 0.f, 0.f, 0.f};
      const f32x4 o = __builtin_amdgcn_mfma_f32_16x16x16f16(cf, bf, z4, 0, 0, 0);
      const float* xp = x + (size_t)(row0 + g * 4) * DIM + dcol0 + rA;
      float* op = out + (size_t)(row0 + g * 4) * DIM + dcol0 + rA;
#pragma unroll
      for (int j = 0; j < 4; ++j)
        op[(size_t)j * DIM] = xp[(size_t)j * DIM] + o[j];
    }
  }
}

extern "C" void kernel_launch(void* const* d_in, const int* in_sizes, int n_in,
                              void* d_out, int out_size, void* d_ws, size_t ws_size,
                              hipStream_t stream) {
  const float* x    = (const float*)d_in[0];
  const float* U    = (const float*)d_in[1];
  const float* V    = (const float*)d_in[2];
  const float* gate = (const float*)d_in[3];
  float* out = (float*)d_out;
  float* prodw = (float*)d_ws;   // 192 floats

  rora_gram<<<192, 256, 0, stream>>>(U, V, prodw);
  rora_fused<<<NTOK / 32, 512, 0, stream>>>(x, U, V, gate, prodw, out);
}

// Round 23
// 49.458 us; speedup vs baseline: 1.0415x; 1.0415x over previous
//
#include <hip/hip_runtime.h>
#include <hip/hip_fp16.h>
#include <cstddef>

#define DIM 2048
#define NTOK 8192
#define NEUMANN_ITERS 6
#define PLANE (DIM / 2 + 1)   // +1 uint4 pad: planes 4 banks apart

// Math (validated rounds 1-22):
//   omega = P Q^T, P=[U|V], Q=[sV|-sU], G = Q^T P  (16x16)
//   Y = (I - G/2)^{-1}(I + G/2)  via Neumann-Horner: Y <- B + 0.5*G*Y, B=I+G/2
//   out = x + c . W^T,  c[r][k] = 0.5*s * sum_j Z[k][j] b[r][j],  Z = I + Y,
//     b[j<8] = av[j], b[j>=8] = -au[j-8];  a = [x.U | x.V] = x.W
//
// r21/r22 lesson: BOTH ran 8 waves/CU — r21: grid 512 x 4-wave = 2 blk/CU
// x 4; r22: grid 256 = 1 blk/CU x 8 (grid too shallow, not LDS!).
// THIS round: 8-wave team owns 16 rows -> grid 512 x 512thr, LDS trimmed
// to 78.9KB (< 80KB: Bm eliminated, B=I+0.5G inline) -> TRUE 2 blocks/CU
// = 16 waves/CU, 2x the TLP of r21/r22.
//   - Phase 1: wave w covers K-slice [w*256,+256) (16 MFMA); Ared[8]
//     reduce. Phase 2: wave w does n-tiles [w*16,+16).
//   - MFMA 16x16x16f16 fragment contracts byte-identical to r21/r22
//     (validated absmax 0.0156/0.031).
//   - 512-thr caps VGPR at 128 (r21/r22 used 60-88 -> no spill).

typedef _Float16 h4 __attribute__((ext_vector_type(4)));
typedef float f32x4 __attribute__((ext_vector_type(4)));

__device__ __forceinline__ unsigned pkh(float lo, float hi) {
  auto p = __builtin_amdgcn_cvt_pkrtz(lo, hi);   // v_cvt_pkrtz_f16_f32
  return __builtin_bit_cast(unsigned, p);
}

// ---------------------------------------------------------------------------
// 1) Gram: one block per entry e=(q,i,j); 256 threads reduce over d=2048.
// ---------------------------------------------------------------------------
__global__ __launch_bounds__(256) void rora_gram(
    const float* __restrict__ U, const float* __restrict__ V,
    float* __restrict__ prod) {
  const int e = blockIdx.x;            // 0..191
  const int q = e >> 6;                // 0: U^T U, 1: U^T V, 2: V^T V
  const int i = (e >> 3) & 7, j = e & 7;
  const float* A = (q == 2) ? V : U;
  const float* B = (q == 0) ? U : V;
  const int t = threadIdx.x;
  float acc = 0.f;
#pragma unroll
  for (int s = 0; s < 8; ++s) {
    const int d = s * 256 + t;
    acc = fmaf(A[d * 8 + i], B[d * 8 + j], acc);
  }
#pragma unroll
  for (int m = 1; m < 64; m <<= 1) acc += __shfl_xor(acc, m, 64);
  __shared__ float wsum[4];
  if ((t & 63) == 0) wsum[t >> 6] = acc;
  __syncthreads();
  if (t == 0) prod[e] = (wsum[0] + wsum[1]) + (wsum[2] + wsum[3]);
}

// ---------------------------------------------------------------------------
// 2) Fused MFMA kernel. uvQ[q][P].comp(m) = half2(W[2P][4q+m], W[2P+1][4q+m]).
//    512 thr = 8 waves, ONE team, 16 rows/block; grid 512 -> 2 blocks/CU.
// ---------------------------------------------------------------------------
__global__ __launch_bounds__(512) void rora_fused(
    const float* __restrict__ x, const float* __restrict__ U,
    const float* __restrict__ V, const float* __restrict__ gate,
    const float* __restrict__ prod, float* __restrict__ out) {
  __shared__ uint4 uvQ[4][PLANE];     // 65,600 B
  __shared__ float prodS[192];        // 768 B
  __shared__ float Gs[16][17];        // 1,088 B
  __shared__ float Ya[16][17];        // 1,088 B
  __shared__ float Yb[16][17];        // 1,088 B
  __shared__ float Ared[8][64][4];    // 8,192 B
  __shared__ float As[16][17];        // 1,088 B   (total 78,912 B < 80 KB)
  const int t = threadIdx.x;          // 0..511
  const int lane = t & 63;
  const int wv = t >> 6;              // 0..7

  // ---- stage U,V -> LDS as f16 d-pairs (4 pairs per thread) ----
  {
    const float4* U4 = (const float4*)U;
    const float4* V4 = (const float4*)V;
#pragma unroll
    for (int rep = 0; rep < 4; ++rep) {
      const int P = rep * 512 + t;    // d-pair (2P, 2P+1); 0..2047
      const float4 a0 = U4[4 * P + 0], a1 = U4[4 * P + 1];
      const float4 a2 = U4[4 * P + 2], a3 = U4[4 * P + 3];
      const float4 b0 = V4[4 * P + 0], b1 = V4[4 * P + 1];
      const float4 b2 = V4[4 * P + 2], b3 = V4[4 * P + 3];
      uvQ[0][P] = make_uint4(pkh(a0.x, a2.x), pkh(a0.y, a2.y),
                             pkh(a0.z, a2.z), pkh(a0.w, a2.w));
      uvQ[1][P] = make_uint4(pkh(a1.x, a3.x), pkh(a1.y, a3.y),
                             pkh(a1.z, a3.z), pkh(a1.w, a3.w));
      uvQ[2][P] = make_uint4(pkh(b0.x, b2.x), pkh(b0.y, b2.y),
                             pkh(b0.z, b2.z), pkh(b0.w, b2.w));
      uvQ[3][P] = make_uint4(pkh(b1.x, b3.x), pkh(b1.y, b3.y),
                             pkh(b1.z, b3.z), pkh(b1.w, b3.w));
    }
  }

  // ---- 16x16 setup (threads 0..255; barriers block-wide) ----
  if (t < 192) prodS[t] = prod[t];
  __syncthreads();
  const float sg = 1.f / (1.f + expf(-gate[0]));
  if (t < 256) {
    const int r = t >> 4, c = t & 15;
    float g;
    if (r < 8) g = (c < 8) ? sg * prodS[64 + c * 8 + r]              // (V^T U)
                           : sg * prodS[128 + r * 8 + (c - 8)];      // (V^T V)
    else       g = (c < 8) ? -sg * prodS[(r - 8) * 8 + c]            // -(U^T U)
                           : -sg * prodS[64 + (r - 8) * 8 + (c - 8)];
    Gs[r][c] = g;
    Ya[r][c] = ((r == c) ? 1.f : 0.f) + 0.5f * g;   // B = I + 0.5G
  }
  __syncthreads();
#pragma unroll
  for (int m = 0; m < NEUMANN_ITERS; ++m) {   // ends in Ya (last m odd)
    if (t < 256) {
      const int r = t >> 4, c = t & 15;
      const float (*Yp)[17] = (m & 1) ? Yb : Ya;
      float (*Yn)[17] = (m & 1) ? Ya : Yb;
      float acc = ((r == c) ? 1.f : 0.f) + 0.5f * Gs[r][c];   // B inline
#pragma unroll
      for (int j = 0; j < 16; ++j)
        acc = fmaf(0.5f * Gs[r][j], Yp[j][c], acc);
      Yn[r][c] = acc;
    }
    __syncthreads();   // final barrier also orders uvQ staging
  }

  // ---- phase 1: a = x.W via MFMA; wave wv covers K-slice [wv*256,+256) ----
  const int row0 = blockIdx.x * 16;
  const int rA = lane & 15, g = lane >> 4;
  f32x4 acc = {0.f, 0.f, 0.f, 0.f};
  {
    const float* xrow = x + (size_t)(row0 + rA) * DIM;
    const int q1 = rA >> 2, c1 = rA & 3;   // B column k = rA
    const unsigned* uvW = (const unsigned*)&uvQ[q1][0];
#pragma unroll 4
    for (int step = 0; step < 16; ++step) {
      const int d0 = wv * 256 + step * 16 + g * 4;
      const float4 xv = *(const float4*)(xrow + d0);
      uint2 au = {pkh(xv.x, xv.y), pkh(xv.z, xv.w)};
      const h4 af = __builtin_bit_cast(h4, au);
      const int P0 = d0 >> 1;
      uint2 bu = {uvW[P0 * 4 + c1], uvW[(P0 + 1) * 4 + c1]};
      const h4 bf = __builtin_bit_cast(h4, bu);
      acc = __builtin_amdgcn_mfma_f32_16x16x16f16(af, bf, acc, 0, 0, 0);
    }
  }
  Ared[wv][lane][0] = acc[0];
  Ared[wv][lane][1] = acc[1];
  Ared[wv][lane][2] = acc[2];
  Ared[wv][lane][3] = acc[3];
  __syncthreads();
  if (t < 256) {
    const int l = t & 63, j = t >> 6;
    float s = 0.f;
#pragma unroll
    for (int w = 0; w < 8; ++w) s += Ared[w][l][j];
    As[(l >> 4) * 4 + j][l & 15] = s;   // a[row][k], D layout per m89
  }
  __syncthreads();

  // ---- c fragment (phase-2 A layout: lane holds c[r=rA][g*4+j]) ----
  h4 cf;
  {
    const float hs = 0.5f * sg;
    const int r = rA;
    float cj[4];
#pragma unroll
    for (int j = 0; j < 4; ++j) {
      const int k = g * 4 + j;
      float s = 0.f;
#pragma unroll
      for (int jj = 0; jj < 8; ++jj) {
        const float zA = Ya[k][jj] + ((k == jj) ? 1.f : 0.f);
        const float zB = Ya[k][8 + jj] + ((k == 8 + jj) ? 1.f : 0.f);
        s = fmaf(zA, As[r][8 + jj], s);    //  Z[k][j']   * av[j']
        s = fmaf(-zB, As[r][jj], s);       // -Z[k][8+j'] * au[j']
      }
      cj[j] = hs * s;
    }
    uint2 cu = {pkh(cj[0], cj[1]), pkh(cj[2], cj[3])};
    cf = __builtin_bit_cast(h4, cu);
  }

  // ---- phase 2: out = x + c.W^T via MFMA; wave wv: n-tiles [wv*16,+16) ----
  {
    const int par = rA & 1;
    for (int nt = wv * 16; nt < wv * 16 + 16; ++nt) {
      const int dcol0 = nt * 16;
      const uint4 wq = uvQ[g][(dcol0 + rA) >> 1];  // plane q = k>>2 = g
      const unsigned w01 = par ? ((wq.x >> 16) | (wq.y & 0xffff0000u))
                               : ((wq.x & 0xffffu) | (wq.y << 16));
      const unsigned w23 = par ? ((wq.z >> 16) | (wq.w & 0xffff0000u))
                               : ((wq.z & 0xffffu) | (wq.w << 16));
      uint2 bu = {w01, w23};
      const h4 bf = __builtin_bit_cast(h4, bu);
      f32x4 z4 = {0.f, 0.f, 0.f, 0.f};
      const f32x4 o = __builtin_amdgcn_mfma_f32_16x16x16f16(cf, bf, z4, 0, 0, 0);
      const float* xp = x + (size_t)(row0 + g * 4) * DIM + dcol0 + rA;
      float* op = out + (size_t)(row0 + g * 4) * DIM + dcol0 + rA;
#pragma unroll
      for (int j = 0; j < 4; ++j)
        op[(size_t)j * DIM] = xp[(size_t)j * DIM] + o[j];
    }
  }
}

extern "C" void kernel_launch(void* const* d_in, const int* in_sizes, int n_in,
                              void* d_out, int out_size, void* d_ws, size_t ws_size,
                              hipStream_t stream) {
  const float* x    = (const float*)d_in[0];
  const float* U    = (const float*)d_in[1];
  const float* V    = (const float*)d_in[2];
  const float* gate = (const float*)d_in[3];
  float* out = (float*)d_out;
  float* prodw = (float*)d_ws;   // 192 floats

  rora_gram<<<192, 256, 0, stream>>>(U, V, prodw);
  rora_fused<<<NTOK / 16, 512, 0, stream>>>(x, U, V, gate, prodw, out);
}

// Round 24
// 43.004 us; speedup vs baseline: 1.1978x; 1.1501x over previous
//
#include <hip/hip_runtime.h>
#include <hip/hip_fp16.h>
#include <cstddef>

#define DIM 2048
#define NTOK 8192
#define NEUMANN_ITERS 6
#define PLANE (DIM / 2 + 1)   // +1 uint4 pad: planes 4 banks apart (r22 fix)

// Math (validated rounds 1-23):
//   omega = P Q^T, P=[U|V], Q=[sV|-sU], G = Q^T P  (16x16)
//   Y = (I - G/2)^{-1}(I + G/2)  via Neumann-Horner: Y <- B + 0.5*G*Y, B=I+G/2
//   out = x + c . W^T,  c[r][k] = 0.5*s * sum_j Z[k][j] b[r][j],  Z = I + Y,
//     b[j<8] = av[j], b[j>=8] = -au[j-8];  a = [x.U | x.V] = x.W
//   NEW (r24): G from in-kernel WtW = W^T W (MFMA on staged f16 uvQ):
//     G[r][c] = r<8 ? +s*WtW[8+r][c] : -s*WtW[r-8][c]
//     (checked against the r1-r23 prodS indexing identity-by-identity).
//
// Geometry: r21's champion (256 thr = 4 waves, 16 rows/block, grid 512,
// fused steady 40.4us) — r22/r23 proved bigger blocks/occupancy DON'T help.
// This round only removes the rora_gram launch (+ws) by computing WtW
// in-preamble: A-frag = B-frag = the validated phase-1 B-gather (identical
// lane mapping row/col = l&15, k = (l>>4)*4+j). f16 gram error ~1e-6 abs.

typedef _Float16 h4 __attribute__((ext_vector_type(4)));
typedef float f32x4 __attribute__((ext_vector_type(4)));

__device__ __forceinline__ unsigned pkh(float lo, float hi) {
  auto p = __builtin_amdgcn_cvt_pkrtz(lo, hi);   // v_cvt_pkrtz_f16_f32
  return __builtin_bit_cast(unsigned, p);
}

// ---------------------------------------------------------------------------
// Fused MFMA kernel. uvQ[q][P].comp(m) = half2(W[2P][4q+m], W[2P+1][4q+m]).
// 256 thr = 4 waves; block owns 16 rows; grid 512. No workspace.
// ---------------------------------------------------------------------------
__global__ __launch_bounds__(256) void rora_fused(
    const float* __restrict__ x, const float* __restrict__ U,
    const float* __restrict__ V, const float* __restrict__ gate,
    float* __restrict__ out) {
  __shared__ uint4 uvQ[4][PLANE];     // 65,600 B
  __shared__ float Gs[16][17];        // 1,088 B
  __shared__ float Ya[16][17];        // 1,088 B
  __shared__ float Yb[16][17];        // 1,088 B
  __shared__ float Wtw[16][17];       // 1,088 B
  __shared__ float Ared[4][64][4];    // 4,096 B
  __shared__ float As[16][17];        // 1,088 B  (total ~75.1 KB)
  const int t = threadIdx.x;
  const int lane = t & 63, wv = t >> 6;
  const int rA = lane & 15, g = lane >> 4;

  // ---- stage U,V -> LDS as f16 d-pairs (4 pairs per thread) ----
  {
    const float4* U4 = (const float4*)U;
    const float4* V4 = (const float4*)V;
#pragma unroll
    for (int rep = 0; rep < 4; ++rep) {
      const int P = rep * 256 + t;    // d-pair (2P, 2P+1); covers 0..1023
      const float4 a0 = U4[4 * P + 0], a1 = U4[4 * P + 1];
      const float4 a2 = U4[4 * P + 2], a3 = U4[4 * P + 3];
      const float4 b0 = V4[4 * P + 0], b1 = V4[4 * P + 1];
      const float4 b2 = V4[4 * P + 2], b3 = V4[4 * P + 3];
      uvQ[0][P] = make_uint4(pkh(a0.x, a2.x), pkh(a0.y, a2.y),
                             pkh(a0.z, a2.z), pkh(a0.w, a2.w));
      uvQ[1][P] = make_uint4(pkh(a1.x, a3.x), pkh(a1.y, a3.y),
                             pkh(a1.z, a3.z), pkh(a1.w, a3.w));
      uvQ[2][P] = make_uint4(pkh(b0.x, b2.x), pkh(b0.y, b2.y),
                             pkh(b0.z, b2.z), pkh(b0.w, b2.w));
      uvQ[3][P] = make_uint4(pkh(b1.x, b3.x), pkh(b1.y, b3.y),
                             pkh(b1.z, b3.z), pkh(b1.w, b3.w));
    }
  }
  __syncthreads();   // staging visible before gram MFMA reads

  // ---- in-kernel gram: WtW = W^T W via MFMA (wave wv: K [wv*512,+512)) ----
  {
    const int q1 = rA >> 2, c1 = rA & 3;   // column k = rA of W
    const unsigned* uvW = (const unsigned*)&uvQ[q1][0];
    f32x4 acc = {0.f, 0.f, 0.f, 0.f};
#pragma unroll 4
    for (int step = 0; step < 32; ++step) {
      const int d0 = wv * 512 + step * 16 + g * 4;
      const int P0 = d0 >> 1;
      uint2 bu = {uvW[P0 * 4 + c1], uvW[(P0 + 1) * 4 + c1]};
      const h4 wf = __builtin_bit_cast(h4, bu);   // W[d0..d0+3][rA]
      acc = __builtin_amdgcn_mfma_f32_16x16x16f16(wf, wf, acc, 0, 0, 0);
    }
    Ared[wv][lane][0] = acc[0];
    Ared[wv][lane][1] = acc[1];
    Ared[wv][lane][2] = acc[2];
    Ared[wv][lane][3] = acc[3];
  }
  __syncthreads();
  {
    const int l = t & 63, j = t >> 6;
    const float s = (Ared[0][l][j] + Ared[1][l][j]) +
                    (Ared[2][l][j] + Ared[3][l][j]);
    Wtw[(l >> 4) * 4 + j][l & 15] = s;   // WtW[i][jcol], D layout per m89
  }
  __syncthreads();

  // ---- G + Neumann setup ----
  const float sg = 1.f / (1.f + expf(-gate[0]));
  {
    const int r = t >> 4, c = t & 15;
    const float gv = (r < 8) ? sg * Wtw[r + 8][c] : -sg * Wtw[r - 8][c];
    Gs[r][c] = gv;
    Ya[r][c] = ((r == c) ? 1.f : 0.f) + 0.5f * gv;   // B = I + 0.5G
  }
  __syncthreads();
#pragma unroll
  for (int m = 0; m < NEUMANN_ITERS; ++m) {   // ends in Ya (last m odd)
    const int r = t >> 4, c = t & 15;
    const float (*Yp)[17] = (m & 1) ? Yb : Ya;
    float (*Yn)[17] = (m & 1) ? Ya : Yb;
    float acc = ((r == c) ? 1.f : 0.f) + 0.5f * Gs[r][c];
#pragma unroll
    for (int j = 0; j < 16; ++j)
      acc = fmaf(0.5f * Gs[r][j], Yp[j][c], acc);
    Yn[r][c] = acc;
    __syncthreads();
  }

  // ---- phase 1: a = x.W via MFMA; wave wv covers K-slice [wv*512,+512) ----
  const int row0 = blockIdx.x * 16;
  f32x4 acc = {0.f, 0.f, 0.f, 0.f};
  {
    const float* xrow = x + (size_t)(row0 + rA) * DIM;
    const int q1 = rA >> 2, c1 = rA & 3;   // B column k = rA
    const unsigned* uvW = (const unsigned*)&uvQ[q1][0];
#pragma unroll 4
    for (int step = 0; step < 32; ++step) {
      const int d0 = wv * 512 + step * 16 + g * 4;
      const float4 xv = *(const float4*)(xrow + d0);
      uint2 au = {pkh(xv.x, xv.y), pkh(xv.z, xv.w)};
      const h4 af = __builtin_bit_cast(h4, au);
      const int P0 = d0 >> 1;
      uint2 bu = {uvW[P0 * 4 + c1], uvW[(P0 + 1) * 4 + c1]};
      const h4 bf = __builtin_bit_cast(h4, bu);
      acc = __builtin_amdgcn_mfma_f32_16x16x16f16(af, bf, acc, 0, 0, 0);
    }
  }
  Ared[wv][lane][0] = acc[0];
  Ared[wv][lane][1] = acc[1];
  Ared[wv][lane][2] = acc[2];
  Ared[wv][lane][3] = acc[3];
  __syncthreads();
  {
    const int l = t & 63, j = t >> 6;
    const float s = (Ared[0][l][j] + Ared[1][l][j]) +
                    (Ared[2][l][j] + Ared[3][l][j]);
    As[(l >> 4) * 4 + j][l & 15] = s;   // a[row][k], D layout per m89
  }
  __syncthreads();

  // ---- c fragment (phase-2 A layout: lane holds c[r=rA][g*4+j]) ----
  h4 cf;
  {
    const float hs = 0.5f * sg;
    const int r = rA;
    float cj[4];
#pragma unroll
    for (int j = 0; j < 4; ++j) {
      const int k = g * 4 + j;
      float s = 0.f;
#pragma unroll
      for (int jj = 0; jj < 8; ++jj) {
        const float zA = Ya[k][jj] + ((k == jj) ? 1.f : 0.f);
        const float zB = Ya[k][8 + jj] + ((k == 8 + jj) ? 1.f : 0.f);
        s = fmaf(zA, As[r][8 + jj], s);    //  Z[k][j']   * av[j']
        s = fmaf(-zB, As[r][jj], s);       // -Z[k][8+j'] * au[j']
      }
      cj[j] = hs * s;
    }
    uint2 cu = {pkh(cj[0], cj[1]), pkh(cj[2], cj[3])};
    cf = __builtin_bit_cast(h4, cu);
  }

  // ---- phase 2: out = x + c.W^T via MFMA; wave wv does 32 n-tiles ----
  {
    const int par = rA & 1;
    for (int nt = wv * 32; nt < wv * 32 + 32; ++nt) {
      const int dcol0 = nt * 16;
      const uint4 wq = uvQ[g][(dcol0 + rA) >> 1];  // plane q = k>>2 = g
      const unsigned w01 = par ? ((wq.x >> 16) | (wq.y & 0xffff0000u))
                               : ((wq.x & 0xffffu) | (wq.y << 16));
      const unsigned w23 = par ? ((wq.z >> 16) | (wq.w & 0xffff0000u))
                               : ((wq.z & 0xffffu) | (wq.w << 16));
      uint2 bu = {w01, w23};
      const h4 bf = __builtin_bit_cast(h4, bu);
      f32x4 z4 = {0.f, 0.f, 0.f, 0.f};
      const f32x4 o = __builtin_amdgcn_mfma_f32_16x16x16f16(cf, bf, z4, 0, 0, 0);
      const float* xp = x + (size_t)(row0 + g * 4) * DIM + dcol0 + rA;
      float* op = out + (size_t)(row0 + g * 4) * DIM + dcol0 + rA;
#pragma unroll
      for (int j = 0; j < 4; ++j)
        op[(size_t)j * DIM] = xp[(size_t)j * DIM] + o[j];
    }
  }
}

extern "C" void kernel_launch(void* const* d_in, const int* in_sizes, int n_in,
                              void* d_out, int out_size, void* d_ws, size_t ws_size,
                              hipStream_t stream) {
  const float* x    = (const float*)d_in[0];
  const float* U    = (const float*)d_in[1];
  const float* V    = (const float*)d_in[2];
  const float* gate = (const float*)d_in[3];
  float* out = (float*)d_out;

  rora_fused<<<NTOK / 16, 256, 0, stream>>>(x, U, V, gate, out);
}

// Round 25
// 41.514 us; speedup vs baseline: 1.2408x; 1.0359x over previous
//
#include <hip/hip_runtime.h>
#include <hip/hip_fp16.h>
#include <cstddef>

#define DIM 2048
#define NTOK 8192
#define NEUMANN_ITERS 6
#define PLANE (DIM / 2 + 1)   // +1 uint4 pad: planes 4 banks apart (r22 fix)

// Math (validated rounds 1-24):
//   omega = P Q^T, P=[U|V], Q=[sV|-sU], G = Q^T P  (16x16)
//   Y = (I - G/2)^{-1}(I + G/2)  via Neumann-Horner: Y <- B + 0.5*G*Y, B=I+G/2
//   out = x + c . W^T,  c[r][k] = 0.5*s * sum_j Z[k][j] b[r][j],  Z = I + Y,
//     b[j<8] = av[j], b[j>=8] = -au[j-8];  a = [x.U | x.V] = x.W
//   G from in-kernel WtW = W^T W (MFMA on staged f16 uvQ, r24-validated):
//     G[r][c] = r<8 ? +s*WtW[8+r][c] : -s*WtW[r-8][c]
//
// r25 change (on the r24 champion, 43.0us): phase-2 MFMA operand SWAP.
//   16x16x16f16 A/B fragment maps are symmetric (A row=l&15, B col=l&15,
//   k=(l>>4)*4+j — in-practice validated since r21). mfma(bf, cf) gives
//   D[d][r] with lane holding corr[row0+rA][dcol0+g*4+j], j=0..3 =
//   ONE FLOAT4 -> epilogue becomes 1 float4 load + 1 float4 store per
//   n-tile (was 4+4 scalar): 4x fewer phase-2 memory instructions, and
//   stores coalesce into 64B segments (g groups contiguous per row).
// Geometry: 256 thr = 4 waves, 16 rows/block, grid 512 (r22/r23 proved
// bigger blocks/occupancy don't help). No workspace.

typedef _Float16 h4 __attribute__((ext_vector_type(4)));
typedef float f32x4 __attribute__((ext_vector_type(4)));

__device__ __forceinline__ unsigned pkh(float lo, float hi) {
  auto p = __builtin_amdgcn_cvt_pkrtz(lo, hi);   // v_cvt_pkrtz_f16_f32
  return __builtin_bit_cast(unsigned, p);
}

// ---------------------------------------------------------------------------
// Fused MFMA kernel. uvQ[q][P].comp(m) = half2(W[2P][4q+m], W[2P+1][4q+m]).
// 256 thr = 4 waves; block owns 16 rows; grid 512. No workspace.
// ---------------------------------------------------------------------------
__global__ __launch_bounds__(256) void rora_fused(
    const float* __restrict__ x, const float* __restrict__ U,
    const float* __restrict__ V, const float* __restrict__ gate,
    float* __restrict__ out) {
  __shared__ uint4 uvQ[4][PLANE];     // 65,600 B
  __shared__ float Gs[16][17];        // 1,088 B
  __shared__ float Ya[16][17];        // 1,088 B
  __shared__ float Yb[16][17];        // 1,088 B
  __shared__ float Wtw[16][17];       // 1,088 B
  __shared__ float Ared[4][64][4];    // 4,096 B
  __shared__ float As[16][17];        // 1,088 B  (total ~75.1 KB)
  const int t = threadIdx.x;
  const int lane = t & 63, wv = t >> 6;
  const int rA = lane & 15, g = lane >> 4;

  // ---- stage U,V -> LDS as f16 d-pairs (4 pairs per thread) ----
  {
    const float4* U4 = (const float4*)U;
    const float4* V4 = (const float4*)V;
#pragma unroll
    for (int rep = 0; rep < 4; ++rep) {
      const int P = rep * 256 + t;    // d-pair (2P, 2P+1); covers 0..1023
      const float4 a0 = U4[4 * P + 0], a1 = U4[4 * P + 1];
      const float4 a2 = U4[4 * P + 2], a3 = U4[4 * P + 3];
      const float4 b0 = V4[4 * P + 0], b1 = V4[4 * P + 1];
      const float4 b2 = V4[4 * P + 2], b3 = V4[4 * P + 3];
      uvQ[0][P] = make_uint4(pkh(a0.x, a2.x), pkh(a0.y, a2.y),
                             pkh(a0.z, a2.z), pkh(a0.w, a2.w));
      uvQ[1][P] = make_uint4(pkh(a1.x, a3.x), pkh(a1.y, a3.y),
                             pkh(a1.z, a3.z), pkh(a1.w, a3.w));
      uvQ[2][P] = make_uint4(pkh(b0.x, b2.x), pkh(b0.y, b2.y),
                             pkh(b0.z, b2.z), pkh(b0.w, b2.w));
      uvQ[3][P] = make_uint4(pkh(b1.x, b3.x), pkh(b1.y, b3.y),
                             pkh(b1.z, b3.z), pkh(b1.w, b3.w));
    }
  }
  __syncthreads();   // staging visible before gram MFMA reads

  // ---- in-kernel gram: WtW = W^T W via MFMA (wave wv: K [wv*512,+512)) ----
  {
    const int q1 = rA >> 2, c1 = rA & 3;   // column k = rA of W
    const unsigned* uvW = (const unsigned*)&uvQ[q1][0];
    f32x4 acc = {0.f, 0.f, 0.f, 0.f};
#pragma unroll 4
    for (int step = 0; step < 32; ++step) {
      const int d0 = wv * 512 + step * 16 + g * 4;
      const int P0 = d0 >> 1;
      uint2 bu = {uvW[P0 * 4 + c1], uvW[(P0 + 1) * 4 + c1]};
      const h4 wf = __builtin_bit_cast(h4, bu);   // W[d0..d0+3][rA]
      acc = __builtin_amdgcn_mfma_f32_16x16x16f16(wf, wf, acc, 0, 0, 0);
    }
    Ared[wv][lane][0] = acc[0];
    Ared[wv][lane][1] = acc[1];
    Ared[wv][lane][2] = acc[2];
    Ared[wv][lane][3] = acc[3];
  }
  __syncthreads();
  {
    const int l = t & 63, j = t >> 6;
    const float s = (Ared[0][l][j] + Ared[1][l][j]) +
                    (Ared[2][l][j] + Ared[3][l][j]);
    Wtw[(l >> 4) * 4 + j][l & 15] = s;   // WtW[i][jcol], D layout per m89
  }
  __syncthreads();

  // ---- G + Neumann setup ----
  const float sg = 1.f / (1.f + expf(-gate[0]));
  {
    const int r = t >> 4, c = t & 15;
    const float gv = (r < 8) ? sg * Wtw[r + 8][c] : -sg * Wtw[r - 8][c];
    Gs[r][c] = gv;
    Ya[r][c] = ((r == c) ? 1.f : 0.f) + 0.5f * gv;   // B = I + 0.5G
  }
  __syncthreads();
#pragma unroll
  for (int m = 0; m < NEUMANN_ITERS; ++m) {   // ends in Ya (last m odd)
    const int r = t >> 4, c = t & 15;
    const float (*Yp)[17] = (m & 1) ? Yb : Ya;
    float (*Yn)[17] = (m & 1) ? Ya : Yb;
    float acc = ((r == c) ? 1.f : 0.f) + 0.5f * Gs[r][c];
#pragma unroll
    for (int j = 0; j < 16; ++j)
      acc = fmaf(0.5f * Gs[r][j], Yp[j][c], acc);
    Yn[r][c] = acc;
    __syncthreads();
  }

  // ---- phase 1: a = x.W via MFMA; wave wv covers K-slice [wv*512,+512) ----
  const int row0 = blockIdx.x * 16;
  f32x4 acc = {0.f, 0.f, 0.f, 0.f};
  {
    const float* xrow = x + (size_t)(row0 + rA) * DIM;
    const int q1 = rA >> 2, c1 = rA & 3;   // B column k = rA
    const unsigned* uvW = (const unsigned*)&uvQ[q1][0];
#pragma unroll 4
    for (int step = 0; step < 32; ++step) {
      const int d0 = wv * 512 + step * 16 + g * 4;
      const float4 xv = *(const float4*)(xrow + d0);
      uint2 au = {pkh(xv.x, xv.y), pkh(xv.z, xv.w)};
      const h4 af = __builtin_bit_cast(h4, au);
      const int P0 = d0 >> 1;
      uint2 bu = {uvW[P0 * 4 + c1], uvW[(P0 + 1) * 4 + c1]};
      const h4 bf = __builtin_bit_cast(h4, bu);
      acc = __builtin_amdgcn_mfma_f32_16x16x16f16(af, bf, acc, 0, 0, 0);
    }
  }
  Ared[wv][lane][0] = acc[0];
  Ared[wv][lane][1] = acc[1];
  Ared[wv][lane][2] = acc[2];
  Ared[wv][lane][3] = acc[3];
  __syncthreads();
  {
    const int l = t & 63, j = t >> 6;
    const float s = (Ared[0][l][j] + Ared[1][l][j]) +
                    (Ared[2][l][j] + Ared[3][l][j]);
    As[(l >> 4) * 4 + j][l & 15] = s;   // a[row][k], D layout per m89
  }
  __syncthreads();

  // ---- c fragment (lane holds c[r=rA][g*4+j]; serves as B-operand) ----
  h4 cf;
  {
    const float hs = 0.5f * sg;
    const int r = rA;
    float cj[4];
#pragma unroll
    for (int j = 0; j < 4; ++j) {
      const int k = g * 4 + j;
      float s = 0.f;
#pragma unroll
      for (int jj = 0; jj < 8; ++jj) {
        const float zA = Ya[k][jj] + ((k == jj) ? 1.f : 0.f);
        const float zB = Ya[k][8 + jj] + ((k == 8 + jj) ? 1.f : 0.f);
        s = fmaf(zA, As[r][8 + jj], s);    //  Z[k][j']   * av[j']
        s = fmaf(-zB, As[r][jj], s);       // -Z[k][8+j'] * au[j']
      }
      cj[j] = hs * s;
    }
    uint2 cu = {pkh(cj[0], cj[1]), pkh(cj[2], cj[3])};
    cf = __builtin_bit_cast(h4, cu);
  }

  // ---- phase 2: out = x + W.c^T via MFMA (SWAPPED operands) ----
  // D[d][r]: lane holds corr[row0+rA][dcol0+g*4+j] = one float4.
  {
    const int par = rA & 1;
    const float4* x4row = (const float4*)(x + (size_t)(row0 + rA) * DIM);
    float4* o4row = (float4*)(out + (size_t)(row0 + rA) * DIM);
    for (int nt = wv * 32; nt < wv * 32 + 32; ++nt) {
      const int dcol0 = nt * 16;
      const uint4 wq = uvQ[g][(dcol0 + rA) >> 1];  // plane q = k>>2 = g
      const unsigned w01 = par ? ((wq.x >> 16) | (wq.y & 0xffff0000u))
                               : ((wq.x & 0xffffu) | (wq.y << 16));
      const unsigned w23 = par ? ((wq.z >> 16) | (wq.w & 0xffff0000u))
                               : ((wq.z & 0xffffu) | (wq.w << 16));
      uint2 bu = {w01, w23};
      const h4 bf = __builtin_bit_cast(h4, bu);    // W[dcol0+rA][g*4+j]
      f32x4 z4 = {0.f, 0.f, 0.f, 0.f};
      const f32x4 o = __builtin_amdgcn_mfma_f32_16x16x16f16(bf, cf, z4, 0, 0, 0);
      const int q4 = (dcol0 >> 2) + g;             // float4 index in row
      const float4 xv = x4row[q4];
      float4 ov;
      ov.x = xv.x + o[0];
      ov.y = xv.y + o[1];
      ov.z = xv.z + o[2];
      ov.w = xv.w + o[3];
      o4row[q4] = ov;
    }
  }
}

extern "C" void kernel_launch(void* const* d_in, const int* in_sizes, int n_in,
                              void* d_out, int out_size, void* d_ws, size_t ws_size,
                              hipStream_t stream) {
  const float* x    = (const float*)d_in[0];
  const float* U    = (const float*)d_in[1];
  const float* V    = (const float*)d_in[2];
  const float* gate = (const float*)d_in[3];
  float* out = (float*)d_out;

  rora_fused<<<NTOK / 16, 256, 0, stream>>>(x, U, V, gate, out);
}